// Round 3
// baseline (2196.589 us; speedup 1.0000x reference)
//
#include <hip/hip_runtime.h>
#include <hip/hip_bf16.h>
#include <math.h>

// Problem constants (match reference): N=100000, D=128, B=512, M=4, E=10, Q=5, MPT=8
constexpr int D   = 128;
constexpr int M   = 4;
constexpr int E   = 10;
constexpr int Q   = 5;
constexpr int MPT = 8;
constexpr int MXE = M * E;                       // 40
constexpr int TASKS = 1 + MXE + Q + Q * MXE;     // 246 weighted dots per b

// ---------------------------------------------------------------------------
// Kernel 1 (fast path): embW[r][j] = sum_i emb[r][i] * W[i][j] (fp32 vector GEMM)
// W staged fully in LDS (64 KB); 32 rows of emb staged per block (16 KB).
// 256 threads: 32 col-groups (4 cols each) x 8 row-groups (4 rows each).
// 80 KB LDS -> 2 blocks/CU; inner loop is FMA-bound (128 FMA-cyc vs 96 LDS-cyc).
// ---------------------------------------------------------------------------
__global__ __launch_bounds__(256, 2)
void embw_gemm(const float* __restrict__ emb,
               const float* __restrict__ W,
               float* __restrict__ embW,
               int nrows)
{
    __shared__ float sW[D * D];      // 64 KB
    __shared__ float srow[32 * D];   // 16 KB

    // stage W (coalesced float4)
    for (int idx = threadIdx.x; idx < D * D / 4; idx += 256) {
        reinterpret_cast<float4*>(sW)[idx] =
            reinterpret_cast<const float4*>(W)[idx];
    }

    const int jg = threadIdx.x & 31;   // column group: cols 4*jg .. 4*jg+3
    const int rg = threadIdx.x >> 5;   // row group: rows 4*rg .. 4*rg+3 (of 32)

    const int base = blockIdx.x * 32;
    if (base >= nrows) return;
    const int nr = min(32, nrows - base);

    // stage 32 emb rows (coalesced float4)
    for (int idx = threadIdx.x; idx < nr * D / 4; idx += 256) {
        reinterpret_cast<float4*>(srow)[idx] =
            reinterpret_cast<const float4*>(emb + (size_t)base * D)[idx];
    }
    __syncthreads();

    float accx[4] = {0.f, 0.f, 0.f, 0.f};
    float accy[4] = {0.f, 0.f, 0.f, 0.f};
    float accz[4] = {0.f, 0.f, 0.f, 0.f};
    float accw[4] = {0.f, 0.f, 0.f, 0.f};

    for (int i0 = 0; i0 < D; i0 += 4) {
        float4 a4[4];
#pragma unroll
        for (int r = 0; r < 4; ++r)
            a4[r] = *reinterpret_cast<const float4*>(&srow[(rg * 4 + r) * D + i0]);
#pragma unroll
        for (int u = 0; u < 4; ++u) {
            float4 w4 = *reinterpret_cast<const float4*>(&sW[(i0 + u) * D + jg * 4]);
#pragma unroll
            for (int r = 0; r < 4; ++r) {
                float a = (u == 0) ? a4[r].x : (u == 1) ? a4[r].y
                        : (u == 2) ? a4[r].z : a4[r].w;
                accx[r] = fmaf(a, w4.x, accx[r]);
                accy[r] = fmaf(a, w4.y, accy[r]);
                accz[r] = fmaf(a, w4.z, accz[r]);
                accw[r] = fmaf(a, w4.w, accw[r]);
            }
        }
    }

#pragma unroll
    for (int r = 0; r < 4; ++r) {
        int row = base + rg * 4 + r;
        if (row < nrows) {
            float4 o = make_float4(accx[r], accy[r], accz[r], accw[r]);
            *reinterpret_cast<float4*>(&embW[(size_t)row * D + jg * 4]) = o;
        }
    }
}

// ---------------------------------------------------------------------------
// Shared device helpers for the pair phase
// ---------------------------------------------------------------------------
__device__ __forceinline__ void block_softmaxes(const float* distance_att,
                                                const float* metapath_att,
                                                float* s_dis, float* s_mp,
                                                int tid)
{
    if (tid == 0) {
        float v[E];
        float mx = -1e30f;
        for (int i = 0; i < E; ++i) { v[i] = distance_att[i]; mx = fmaxf(mx, v[i]); }
        float sum = 0.f;
        for (int i = 0; i < E; ++i) { v[i] = expf(v[i] - mx); sum += v[i]; }
        for (int i = 0; i < E; ++i) s_dis[i] = v[i] / sum;

        float w[MPT];
        mx = -1e30f;
        for (int i = 0; i < MPT; ++i) { w[i] = metapath_att[i]; mx = fmaxf(mx, w[i]); }
        sum = 0.f;
        for (int i = 0; i < MPT; ++i) { w[i] = expf(w[i] - mx); sum += w[i]; }
        for (int i = 0; i < MPT; ++i) s_mp[i] = w[i] / sum;
    }
}

// Decode a task id into (src, dst, slot, weight).
__device__ __forceinline__ void decode_task(
    int task, int b, int s, int t, float tt, float dss, float dsdt,
    const float* __restrict__ delta,
    const float* __restrict__ s_dis, const float* __restrict__ s_mp,
    const int* __restrict__ mp_src, const int* __restrict__ mp_dst,
    const float* __restrict__ mp_time, const int* __restrict__ mp_dist,
    const int* __restrict__ mp_type,
    const int* __restrict__ neg_node,
    const int* __restrict__ neg_mp_src, const int* __restrict__ neg_mp_dst,
    const float* __restrict__ neg_mp_time, const int* __restrict__ neg_mp_dist,
    const int* __restrict__ neg_mp_type,
    int& srcn, int& dstn, int& slot, float& wgt)
{
    if (task == 0) {
        srcn = s; dstn = t; slot = 0; wgt = 1.f;
    } else if (task <= MXE) {
        int pe = task - 1;          // pe = m*E + e
        int m  = pe / E;
        int idx = b * MXE + pe;
        srcn = mp_src[idx];
        dstn = mp_dst[idx];
        slot = 0;
        float dec = expf(-dsdt * fabsf(tt - mp_time[idx]));
        wgt = s_dis[mp_dist[idx]] * dec * s_mp[mp_type[b * M + m]];
    } else if (task <= MXE + Q) {
        int q = task - 1 - MXE;
        srcn = s;                   // bilinear src is s (asymmetric!)
        dstn = neg_node[b * Q + q];
        slot = 1 + q;
        wgt  = 1.f;
    } else {
        int ne  = task - 1 - MXE - Q;   // ne = q*MXE + m*E + e
        int q   = ne / MXE;
        int rem = ne - q * MXE;
        int m   = rem / E;
        int idx = (b * Q + q) * MXE + rem;
        srcn = neg_mp_src[idx];
        dstn = neg_mp_dst[idx];
        slot = 1 + q;
        float dneg = delta[neg_node[b * Q + q]];
        float dec  = expf(-(dss * dneg) * fabsf(tt - neg_mp_time[idx]));
        wgt = s_dis[neg_mp_dist[idx]] * dec * s_mp[neg_mp_type[(b * Q + q) * M + m]];
    }
}

__device__ __forceinline__ void epilogue(const float* slots, float* out, int b)
{
    const float eps = 1e-6f;
    float p = slots[0];
    float loss = -logf(1.f / (1.f + expf(-p)) + eps);
#pragma unroll
    for (int q = 0; q < Q; ++q) {
        float v = slots[1 + q];
        loss -= logf(1.f / (1.f + expf(v)) + eps);   // log(sigmoid(-v)+eps)
    }
    out[b] = loss;
}

// ---------------------------------------------------------------------------
// Kernel 2 (fast path): per-b weighted-dot accumulation + log-sigmoid epilogue.
// One block (512 threads = 32 x 16-lane subgroups) per b.
// Each subgroup handles tasks sg, sg+32, ...; a task is one 128-dim dot
// dot(embW[src], emb[dst]) scaled by a per-task weight, accumulated into
// LDS slot 0 (p_lambda) or slot 1+q (neg val q).
// ---------------------------------------------------------------------------
__global__ __launch_bounds__(512)
void pair_kernel(const float* __restrict__ emb,
                 const float* __restrict__ embW,
                 const float* __restrict__ delta,
                 const float* __restrict__ distance_att,
                 const float* __restrict__ metapath_att,
                 const int*   __restrict__ s_node,
                 const int*   __restrict__ t_node,
                 const float* __restrict__ s_t_time,
                 const int*   __restrict__ mp_src,
                 const int*   __restrict__ mp_dst,
                 const float* __restrict__ mp_time,
                 const int*   __restrict__ mp_dist,
                 const int*   __restrict__ mp_type,
                 const int*   __restrict__ neg_node,
                 const int*   __restrict__ neg_mp_src,
                 const int*   __restrict__ neg_mp_dst,
                 const float* __restrict__ neg_mp_time,
                 const int*   __restrict__ neg_mp_dist,
                 const int*   __restrict__ neg_mp_type,
                 float* __restrict__ out)
{
    __shared__ float slots[1 + Q];
    __shared__ float s_dis[E];
    __shared__ float s_mp[MPT];

    const int b   = blockIdx.x;
    const int tid = threadIdx.x;

    if (tid < 1 + Q) slots[tid] = 0.f;
    block_softmaxes(distance_att, metapath_att, s_dis, s_mp, tid);
    __syncthreads();

    const int   s    = s_node[b];
    const int   t    = t_node[b];
    const float tt   = s_t_time[b];
    const float dss  = delta[s];
    const float dsdt = dss * delta[t];

    const int sg = tid >> 4;   // subgroup 0..31
    const int ln = tid & 15;   // lane in subgroup

    for (int task = sg; task < TASKS; task += 32) {
        int srcn, dstn, slot;
        float wgt;
        decode_task(task, b, s, t, tt, dss, dsdt, delta, s_dis, s_mp,
                    mp_src, mp_dst, mp_time, mp_dist, mp_type,
                    neg_node, neg_mp_src, neg_mp_dst, neg_mp_time,
                    neg_mp_dist, neg_mp_type, srcn, dstn, slot, wgt);

        // 128-dim dot: 16 lanes x 8 elements (2x float4 each side)
        const float4* pa = reinterpret_cast<const float4*>(embW + (size_t)srcn * D + ln * 8);
        const float4* pb = reinterpret_cast<const float4*>(emb  + (size_t)dstn * D + ln * 8);
        float4 a0 = pa[0], a1 = pa[1];
        float4 b0 = pb[0], b1 = pb[1];
        float d = a0.x * b0.x + a0.y * b0.y + a0.z * b0.z + a0.w * b0.w
                + a1.x * b1.x + a1.y * b1.y + a1.z * b1.z + a1.w * b1.w;
        d += __shfl_xor(d, 8);
        d += __shfl_xor(d, 4);
        d += __shfl_xor(d, 2);
        d += __shfl_xor(d, 1);
        if (ln == 0) atomicAdd(&slots[slot], d * wgt);
    }
    __syncthreads();

    if (tid == 0) epilogue(slots, out, b);
}

// ---------------------------------------------------------------------------
// Fallback (workspace too small): one wave per task; computes v = emb[src]@W
// on the fly (each lane owns 2 columns of W), then dot(v, emb[dst]).
// One block (512 threads = 8 waves) per b.
// ---------------------------------------------------------------------------
__global__ __launch_bounds__(512)
void pair_direct(const float* __restrict__ emb,
                 const float* __restrict__ W,
                 const float* __restrict__ delta,
                 const float* __restrict__ distance_att,
                 const float* __restrict__ metapath_att,
                 const int*   __restrict__ s_node,
                 const int*   __restrict__ t_node,
                 const float* __restrict__ s_t_time,
                 const int*   __restrict__ mp_src,
                 const int*   __restrict__ mp_dst,
                 const float* __restrict__ mp_time,
                 const int*   __restrict__ mp_dist,
                 const int*   __restrict__ mp_type,
                 const int*   __restrict__ neg_node,
                 const int*   __restrict__ neg_mp_src,
                 const int*   __restrict__ neg_mp_dst,
                 const float* __restrict__ neg_mp_time,
                 const int*   __restrict__ neg_mp_dist,
                 const int*   __restrict__ neg_mp_type,
                 float* __restrict__ out)
{
    __shared__ float slots[1 + Q];
    __shared__ float s_dis[E];
    __shared__ float s_mp[MPT];

    const int b   = blockIdx.x;
    const int tid = threadIdx.x;

    if (tid < 1 + Q) slots[tid] = 0.f;
    block_softmaxes(distance_att, metapath_att, s_dis, s_mp, tid);
    __syncthreads();

    const int   s    = s_node[b];
    const int   t    = t_node[b];
    const float tt   = s_t_time[b];
    const float dss  = delta[s];
    const float dsdt = dss * delta[t];

    const int wave = tid >> 6;   // 0..7
    const int ln   = tid & 63;   // lane in wave

    for (int task = wave; task < TASKS; task += 8) {
        int srcn, dstn, slot;
        float wgt;
        decode_task(task, b, s, t, tt, dss, dsdt, delta, s_dis, s_mp,
                    mp_src, mp_dst, mp_time, mp_dist, mp_type,
                    neg_node, neg_mp_src, neg_mp_dst, neg_mp_time,
                    neg_mp_dist, neg_mp_type, srcn, dstn, slot, wgt);

        // v[j] = sum_i emb[src][i] * W[i][j]; lane ln owns cols ln and ln+64
        const float* erow = emb + (size_t)srcn * D;
        float v0 = 0.f, v1 = 0.f;
        for (int i = 0; i < D; ++i) {
            float a = erow[i];                    // broadcast across wave
            v0 = fmaf(a, W[i * D + ln], v0);      // coalesced 64-lane read
            v1 = fmaf(a, W[i * D + ln + 64], v1);
        }
        const float* drow = emb + (size_t)dstn * D;
        float d = v0 * drow[ln] + v1 * drow[ln + 64];
        // full 64-lane reduce
        d += __shfl_xor(d, 32);
        d += __shfl_xor(d, 16);
        d += __shfl_xor(d, 8);
        d += __shfl_xor(d, 4);
        d += __shfl_xor(d, 2);
        d += __shfl_xor(d, 1);
        if (ln == 0) atomicAdd(&slots[slot], d * wgt);
    }
    __syncthreads();

    if (tid == 0) epilogue(slots, out, b);
}

// ---------------------------------------------------------------------------
extern "C" void kernel_launch(void* const* d_in, const int* in_sizes, int n_in,
                              void* d_out, int out_size, void* d_ws, size_t ws_size,
                              hipStream_t stream)
{
    const float* emb          = (const float*)d_in[0];
    const float* delta        = (const float*)d_in[1];
    const float* W            = (const float*)d_in[2];
    const float* distance_att = (const float*)d_in[3];
    const float* metapath_att = (const float*)d_in[4];
    const int*   s_node       = (const int*)d_in[5];
    const int*   t_node       = (const int*)d_in[6];
    const float* s_t_time     = (const float*)d_in[7];
    const int*   mp_src       = (const int*)d_in[8];
    const int*   mp_dst       = (const int*)d_in[9];
    const float* mp_time      = (const float*)d_in[10];
    const int*   mp_dist      = (const int*)d_in[11];
    const int*   mp_type      = (const int*)d_in[12];
    const int*   neg_node     = (const int*)d_in[13];
    const int*   neg_mp_src   = (const int*)d_in[14];
    const int*   neg_mp_dst   = (const int*)d_in[15];
    const float* neg_mp_time  = (const float*)d_in[16];
    const int*   neg_mp_dist  = (const int*)d_in[17];
    const int*   neg_mp_type  = (const int*)d_in[18];

    const int N = in_sizes[1];       // delta has N elements
    const int B = in_sizes[5];       // s_node has B elements

    const size_t need = (size_t)N * D * sizeof(float);   // 51.2 MB

    if (ws_size >= need) {
        // Fast path: precompute embW = emb @ W, then gather-dots.
        float* embW = (float*)d_ws;
        int blocks1 = (N + 31) / 32;
        embw_gemm<<<blocks1, 256, 0, stream>>>(emb, W, embW, N);
        pair_kernel<<<B, 512, 0, stream>>>(emb, embW, delta,
                                           distance_att, metapath_att,
                                           s_node, t_node, s_t_time,
                                           mp_src, mp_dst, mp_time, mp_dist, mp_type,
                                           neg_node, neg_mp_src, neg_mp_dst,
                                           neg_mp_time, neg_mp_dist, neg_mp_type,
                                           (float*)d_out);
    } else {
        // Fallback: direct evaluation, no workspace needed.
        pair_direct<<<B, 512, 0, stream>>>(emb, W, delta,
                                           distance_att, metapath_att,
                                           s_node, t_node, s_t_time,
                                           mp_src, mp_dst, mp_time, mp_dist, mp_type,
                                           neg_node, neg_mp_src, neg_mp_dst,
                                           neg_mp_time, neg_mp_dist, neg_mp_type,
                                           (float*)d_out);
    }
}

// Round 5
// 191.170 us; speedup vs baseline: 11.4902x; 11.4902x over previous
//
#include <hip/hip_runtime.h>
#include <hip/hip_bf16.h>
#include <math.h>

// Problem constants (match reference): N=100000, D=128, B=512, M=4, E=10, Q=5, MPT=8
constexpr int D   = 128;
constexpr int M   = 4;
constexpr int E   = 10;
constexpr int Q   = 5;
constexpr int MPT = 8;
constexpr int MXE = M * E;                       // 40
constexpr int TASKS = 1 + MXE + Q + Q * MXE;     // 246 weighted dots per b

// ---------------------------------------------------------------------------
// Kernel 1 (fast path): embW[r][j] = sum_i emb[r][i] * W[i][j] (fp32 vector GEMM)
// W staged fully in LDS (64 KB); 32 rows of emb staged per block (16 KB).
// 256 threads: 32 col-groups (4 cols each) x 8 row-groups (4 rows each).
//
// ROUND-3 FIX (unmeasured, resubmitted): `#pragma unroll 1` on the K-loop.
// The round-2 version let -O3 fully unroll the 32-trip loop -> ~128 hoisted
// ds_read_b128 (~4KB/thread live) -> allocator spill to scratch -> 5.8 GB
// HBM traffic/dispatch (4.3KB fetch + 2.7KB write per thread), VALUBusy 1.4%,
// 2090 us + 32ms cold first dispatch. Live set now ~40 VGPRs; no spill.
// ---------------------------------------------------------------------------
__global__ __launch_bounds__(256, 2)
void embw_gemm(const float* __restrict__ emb,
               const float* __restrict__ W,
               float* __restrict__ embW,
               int nrows)
{
    __shared__ float sW[D * D];      // 64 KB
    __shared__ float srow[32 * D];   // 16 KB

    // stage W (coalesced float4)
    for (int idx = threadIdx.x; idx < D * D / 4; idx += 256) {
        reinterpret_cast<float4*>(sW)[idx] =
            reinterpret_cast<const float4*>(W)[idx];
    }

    const int jg = threadIdx.x & 31;   // column group: cols 4*jg .. 4*jg+3
    const int rg = threadIdx.x >> 5;   // row group: rows 4*rg .. 4*rg+3 (of 32)

    const int base = blockIdx.x * 32;
    if (base >= nrows) return;
    const int nr = min(32, nrows - base);

    // stage 32 emb rows (coalesced float4)
    for (int idx = threadIdx.x; idx < nr * D / 4; idx += 256) {
        reinterpret_cast<float4*>(srow)[idx] =
            reinterpret_cast<const float4*>(emb + (size_t)base * D)[idx];
    }
    __syncthreads();

    float acc0x = 0.f, acc0y = 0.f, acc0z = 0.f, acc0w = 0.f;
    float acc1x = 0.f, acc1y = 0.f, acc1z = 0.f, acc1w = 0.f;
    float acc2x = 0.f, acc2y = 0.f, acc2z = 0.f, acc2w = 0.f;
    float acc3x = 0.f, acc3y = 0.f, acc3z = 0.f, acc3w = 0.f;

    const float* sA = &srow[rg * 4 * D];
    const float* sB = &sW[jg * 4];

#pragma unroll 1
    for (int i0 = 0; i0 < D; i0 += 4) {
        float4 a0 = *reinterpret_cast<const float4*>(&sA[0 * D + i0]);
        float4 a1 = *reinterpret_cast<const float4*>(&sA[1 * D + i0]);
        float4 a2 = *reinterpret_cast<const float4*>(&sA[2 * D + i0]);
        float4 a3 = *reinterpret_cast<const float4*>(&sA[3 * D + i0]);

#pragma unroll
        for (int u = 0; u < 4; ++u) {
            float4 w4 = *reinterpret_cast<const float4*>(&sB[(i0 + u) * D]);
            float e0 = (u == 0) ? a0.x : (u == 1) ? a0.y : (u == 2) ? a0.z : a0.w;
            float e1 = (u == 0) ? a1.x : (u == 1) ? a1.y : (u == 2) ? a1.z : a1.w;
            float e2 = (u == 0) ? a2.x : (u == 1) ? a2.y : (u == 2) ? a2.z : a2.w;
            float e3 = (u == 0) ? a3.x : (u == 1) ? a3.y : (u == 2) ? a3.z : a3.w;
            acc0x = fmaf(e0, w4.x, acc0x); acc0y = fmaf(e0, w4.y, acc0y);
            acc0z = fmaf(e0, w4.z, acc0z); acc0w = fmaf(e0, w4.w, acc0w);
            acc1x = fmaf(e1, w4.x, acc1x); acc1y = fmaf(e1, w4.y, acc1y);
            acc1z = fmaf(e1, w4.z, acc1z); acc1w = fmaf(e1, w4.w, acc1w);
            acc2x = fmaf(e2, w4.x, acc2x); acc2y = fmaf(e2, w4.y, acc2y);
            acc2z = fmaf(e2, w4.z, acc2z); acc2w = fmaf(e2, w4.w, acc2w);
            acc3x = fmaf(e3, w4.x, acc3x); acc3y = fmaf(e3, w4.y, acc3y);
            acc3z = fmaf(e3, w4.z, acc3z); acc3w = fmaf(e3, w4.w, acc3w);
        }
    }

    const int r0 = base + rg * 4;
    if (r0 + 0 < nrows)
        *reinterpret_cast<float4*>(&embW[(size_t)(r0 + 0) * D + jg * 4]) =
            make_float4(acc0x, acc0y, acc0z, acc0w);
    if (r0 + 1 < nrows)
        *reinterpret_cast<float4*>(&embW[(size_t)(r0 + 1) * D + jg * 4]) =
            make_float4(acc1x, acc1y, acc1z, acc1w);
    if (r0 + 2 < nrows)
        *reinterpret_cast<float4*>(&embW[(size_t)(r0 + 2) * D + jg * 4]) =
            make_float4(acc2x, acc2y, acc2z, acc2w);
    if (r0 + 3 < nrows)
        *reinterpret_cast<float4*>(&embW[(size_t)(r0 + 3) * D + jg * 4]) =
            make_float4(acc3x, acc3y, acc3z, acc3w);
}

// ---------------------------------------------------------------------------
// Shared device helpers for the pair phase
// ---------------------------------------------------------------------------
__device__ __forceinline__ void block_softmaxes(const float* distance_att,
                                                const float* metapath_att,
                                                float* s_dis, float* s_mp,
                                                int tid)
{
    if (tid == 0) {
        float v[E];
        float mx = -1e30f;
        for (int i = 0; i < E; ++i) { v[i] = distance_att[i]; mx = fmaxf(mx, v[i]); }
        float sum = 0.f;
        for (int i = 0; i < E; ++i) { v[i] = expf(v[i] - mx); sum += v[i]; }
        for (int i = 0; i < E; ++i) s_dis[i] = v[i] / sum;

        float w[MPT];
        mx = -1e30f;
        for (int i = 0; i < MPT; ++i) { w[i] = metapath_att[i]; mx = fmaxf(mx, w[i]); }
        sum = 0.f;
        for (int i = 0; i < MPT; ++i) { w[i] = expf(w[i] - mx); sum += w[i]; }
        for (int i = 0; i < MPT; ++i) s_mp[i] = w[i] / sum;
    }
}

// Decode a task id into (src, dst, slot, weight).
__device__ __forceinline__ void decode_task(
    int task, int b, int s, int t, float tt, float dss, float dsdt,
    const float* __restrict__ delta,
    const float* __restrict__ s_dis, const float* __restrict__ s_mp,
    const int* __restrict__ mp_src, const int* __restrict__ mp_dst,
    const float* __restrict__ mp_time, const int* __restrict__ mp_dist,
    const int* __restrict__ mp_type,
    const int* __restrict__ neg_node,
    const int* __restrict__ neg_mp_src, const int* __restrict__ neg_mp_dst,
    const float* __restrict__ neg_mp_time, const int* __restrict__ neg_mp_dist,
    const int* __restrict__ neg_mp_type,
    int& srcn, int& dstn, int& slot, float& wgt)
{
    if (task == 0) {
        srcn = s; dstn = t; slot = 0; wgt = 1.f;
    } else if (task <= MXE) {
        int pe = task - 1;          // pe = m*E + e
        int m  = pe / E;
        int idx = b * MXE + pe;
        srcn = mp_src[idx];
        dstn = mp_dst[idx];
        slot = 0;
        float dec = expf(-dsdt * fabsf(tt - mp_time[idx]));
        wgt = s_dis[mp_dist[idx]] * dec * s_mp[mp_type[b * M + m]];
    } else if (task <= MXE + Q) {
        int q = task - 1 - MXE;
        srcn = s;                   // bilinear src is s (asymmetric!)
        dstn = neg_node[b * Q + q];
        slot = 1 + q;
        wgt  = 1.f;
    } else {
        int ne  = task - 1 - MXE - Q;   // ne = q*MXE + m*E + e
        int q   = ne / MXE;
        int rem = ne - q * MXE;
        int m   = rem / E;
        int idx = (b * Q + q) * MXE + rem;
        srcn = neg_mp_src[idx];
        dstn = neg_mp_dst[idx];
        slot = 1 + q;
        float dneg = delta[neg_node[b * Q + q]];
        float dec  = expf(-(dss * dneg) * fabsf(tt - neg_mp_time[idx]));
        wgt = s_dis[neg_mp_dist[idx]] * dec * s_mp[neg_mp_type[(b * Q + q) * M + m]];
    }
}

__device__ __forceinline__ void epilogue(const float* slots, float* out, int b)
{
    const float eps = 1e-6f;
    float p = slots[0];
    float loss = -logf(1.f / (1.f + expf(-p)) + eps);
#pragma unroll
    for (int q = 0; q < Q; ++q) {
        float v = slots[1 + q];
        loss -= logf(1.f / (1.f + expf(v)) + eps);   // log(sigmoid(-v)+eps)
    }
    out[b] = loss;
}

// ---------------------------------------------------------------------------
// Kernel 2 (fast path): per-b weighted-dot accumulation + log-sigmoid epilogue.
// One block (512 threads = 32 x 16-lane subgroups) per b.
// ---------------------------------------------------------------------------
__global__ __launch_bounds__(512)
void pair_kernel(const float* __restrict__ emb,
                 const float* __restrict__ embW,
                 const float* __restrict__ delta,
                 const float* __restrict__ distance_att,
                 const float* __restrict__ metapath_att,
                 const int*   __restrict__ s_node,
                 const int*   __restrict__ t_node,
                 const float* __restrict__ s_t_time,
                 const int*   __restrict__ mp_src,
                 const int*   __restrict__ mp_dst,
                 const float* __restrict__ mp_time,
                 const int*   __restrict__ mp_dist,
                 const int*   __restrict__ mp_type,
                 const int*   __restrict__ neg_node,
                 const int*   __restrict__ neg_mp_src,
                 const int*   __restrict__ neg_mp_dst,
                 const float* __restrict__ neg_mp_time,
                 const int*   __restrict__ neg_mp_dist,
                 const int*   __restrict__ neg_mp_type,
                 float* __restrict__ out)
{
    __shared__ float slots[1 + Q];
    __shared__ float s_dis[E];
    __shared__ float s_mp[MPT];

    const int b   = blockIdx.x;
    const int tid = threadIdx.x;

    if (tid < 1 + Q) slots[tid] = 0.f;
    block_softmaxes(distance_att, metapath_att, s_dis, s_mp, tid);
    __syncthreads();

    const int   s    = s_node[b];
    const int   t    = t_node[b];
    const float tt   = s_t_time[b];
    const float dss  = delta[s];
    const float dsdt = dss * delta[t];

    const int sg = tid >> 4;   // subgroup 0..31
    const int ln = tid & 15;   // lane in subgroup

    for (int task = sg; task < TASKS; task += 32) {
        int srcn, dstn, slot;
        float wgt;
        decode_task(task, b, s, t, tt, dss, dsdt, delta, s_dis, s_mp,
                    mp_src, mp_dst, mp_time, mp_dist, mp_type,
                    neg_node, neg_mp_src, neg_mp_dst, neg_mp_time,
                    neg_mp_dist, neg_mp_type, srcn, dstn, slot, wgt);

        // 128-dim dot: 16 lanes x 8 elements (2x float4 each side)
        const float4* pa = reinterpret_cast<const float4*>(embW + (size_t)srcn * D + ln * 8);
        const float4* pb = reinterpret_cast<const float4*>(emb  + (size_t)dstn * D + ln * 8);
        float4 a0 = pa[0], a1 = pa[1];
        float4 b0 = pb[0], b1 = pb[1];
        float d = a0.x * b0.x + a0.y * b0.y + a0.z * b0.z + a0.w * b0.w
                + a1.x * b1.x + a1.y * b1.y + a1.z * b1.z + a1.w * b1.w;
        d += __shfl_xor(d, 8);
        d += __shfl_xor(d, 4);
        d += __shfl_xor(d, 2);
        d += __shfl_xor(d, 1);
        if (ln == 0) atomicAdd(&slots[slot], d * wgt);
    }
    __syncthreads();

    if (tid == 0) epilogue(slots, out, b);
}

// ---------------------------------------------------------------------------
// Fallback (workspace too small): one wave per task; computes v = emb[src]@W
// on the fly (each lane owns 2 columns of W), then dot(v, emb[dst]).
// One block (512 threads = 8 waves) per b.
// ---------------------------------------------------------------------------
__global__ __launch_bounds__(512)
void pair_direct(const float* __restrict__ emb,
                 const float* __restrict__ W,
                 const float* __restrict__ delta,
                 const float* __restrict__ distance_att,
                 const float* __restrict__ metapath_att,
                 const int*   __restrict__ s_node,
                 const int*   __restrict__ t_node,
                 const float* __restrict__ s_t_time,
                 const int*   __restrict__ mp_src,
                 const int*   __restrict__ mp_dst,
                 const float* __restrict__ mp_time,
                 const int*   __restrict__ mp_dist,
                 const int*   __restrict__ mp_type,
                 const int*   __restrict__ neg_node,
                 const int*   __restrict__ neg_mp_src,
                 const int*   __restrict__ neg_mp_dst,
                 const float* __restrict__ neg_mp_time,
                 const int*   __restrict__ neg_mp_dist,
                 const int*   __restrict__ neg_mp_type,
                 float* __restrict__ out)
{
    __shared__ float slots[1 + Q];
    __shared__ float s_dis[E];
    __shared__ float s_mp[MPT];

    const int b   = blockIdx.x;
    const int tid = threadIdx.x;

    if (tid < 1 + Q) slots[tid] = 0.f;
    block_softmaxes(distance_att, metapath_att, s_dis, s_mp, tid);
    __syncthreads();

    const int   s    = s_node[b];
    const int   t    = t_node[b];
    const float tt   = s_t_time[b];
    const float dss  = delta[s];
    const float dsdt = dss * delta[t];

    const int wave = tid >> 6;   // 0..7
    const int ln   = tid & 63;   // lane in wave

    for (int task = wave; task < TASKS; task += 8) {
        int srcn, dstn, slot;
        float wgt;
        decode_task(task, b, s, t, tt, dss, dsdt, delta, s_dis, s_mp,
                    mp_src, mp_dst, mp_time, mp_dist, mp_type,
                    neg_node, neg_mp_src, neg_mp_dst, neg_mp_time,
                    neg_mp_dist, neg_mp_type, srcn, dstn, slot, wgt);

        // v[j] = sum_i emb[src][i] * W[i][j]; lane ln owns cols ln and ln+64
        const float* erow = emb + (size_t)srcn * D;
        float v0 = 0.f, v1 = 0.f;
#pragma unroll 1
        for (int i = 0; i < D; ++i) {
            float a = erow[i];                    // broadcast across wave
            v0 = fmaf(a, W[i * D + ln], v0);      // coalesced 64-lane read
            v1 = fmaf(a, W[i * D + ln + 64], v1);
        }
        const float* drow = emb + (size_t)dstn * D;
        float d = v0 * drow[ln] + v1 * drow[ln + 64];
        // full 64-lane reduce
        d += __shfl_xor(d, 32);
        d += __shfl_xor(d, 16);
        d += __shfl_xor(d, 8);
        d += __shfl_xor(d, 4);
        d += __shfl_xor(d, 2);
        d += __shfl_xor(d, 1);
        if (ln == 0) atomicAdd(&slots[slot], d * wgt);
    }
    __syncthreads();

    if (tid == 0) epilogue(slots, out, b);
}

// ---------------------------------------------------------------------------
extern "C" void kernel_launch(void* const* d_in, const int* in_sizes, int n_in,
                              void* d_out, int out_size, void* d_ws, size_t ws_size,
                              hipStream_t stream)
{
    const float* emb          = (const float*)d_in[0];
    const float* delta        = (const float*)d_in[1];
    const float* W            = (const float*)d_in[2];
    const float* distance_att = (const float*)d_in[3];
    const float* metapath_att = (const float*)d_in[4];
    const int*   s_node       = (const int*)d_in[5];
    const int*   t_node       = (const int*)d_in[6];
    const float* s_t_time     = (const float*)d_in[7];
    const int*   mp_src       = (const int*)d_in[8];
    const int*   mp_dst       = (const int*)d_in[9];
    const float* mp_time      = (const float*)d_in[10];
    const int*   mp_dist      = (const int*)d_in[11];
    const int*   mp_type      = (const int*)d_in[12];
    const int*   neg_node     = (const int*)d_in[13];
    const int*   neg_mp_src   = (const int*)d_in[14];
    const int*   neg_mp_dst   = (const int*)d_in[15];
    const float* neg_mp_time  = (const float*)d_in[16];
    const int*   neg_mp_dist  = (const int*)d_in[17];
    const int*   neg_mp_type  = (const int*)d_in[18];

    const int N = in_sizes[1];       // delta has N elements
    const int B = in_sizes[5];       // s_node has B elements

    const size_t need = (size_t)N * D * sizeof(float);   // 51.2 MB

    if (ws_size >= need) {
        // Fast path: precompute embW = emb @ W, then gather-dots.
        float* embW = (float*)d_ws;
        int blocks1 = (N + 31) / 32;
        embw_gemm<<<blocks1, 256, 0, stream>>>(emb, W, embW, N);
        pair_kernel<<<B, 512, 0, stream>>>(emb, embW, delta,
                                           distance_att, metapath_att,
                                           s_node, t_node, s_t_time,
                                           mp_src, mp_dst, mp_time, mp_dist, mp_type,
                                           neg_node, neg_mp_src, neg_mp_dst,
                                           neg_mp_time, neg_mp_dist, neg_mp_type,
                                           (float*)d_out);
    } else {
        // Fallback: direct evaluation, no workspace needed.
        pair_direct<<<B, 512, 0, stream>>>(emb, W, delta,
                                           distance_att, metapath_att,
                                           s_node, t_node, s_t_time,
                                           mp_src, mp_dst, mp_time, mp_dist, mp_type,
                                           neg_node, neg_mp_src, neg_mp_dst,
                                           neg_mp_time, neg_mp_dist, neg_mp_type,
                                           (float*)d_out);
    }
}

// Round 9
// 185.868 us; speedup vs baseline: 11.8180x; 1.0285x over previous
//
#include <hip/hip_runtime.h>
#include <hip/hip_bf16.h>
#include <math.h>

// Problem constants (match reference): N=100000, D=128, B=512, M=4, E=10, Q=5, MPT=8
constexpr int D   = 128;
constexpr int M   = 4;
constexpr int E   = 10;
constexpr int Q   = 5;
constexpr int MPT = 8;
constexpr int MXE = M * E;                       // 40
constexpr int TASKS = 1 + MXE + Q + Q * MXE;     // 246 weighted dots per b

// ---------------------------------------------------------------------------
// Kernel 1: embW = emb @ W  (fp32, no fp32 MFMA on CDNA4 -> vector FMA)
//
// ROUND-5 REDESIGN (r4: 76us, VALUBusy 39%, LDS-pipe-bound), resubmitted
// unmeasured (round-6/7/8 broker timeouts):
//  - 8x8 thread tiles, 128-row blocks: FMA 512 cyc/wave-iter vs 8 W-ds_read
//    (~96 LDS-cyc) -> VALU-bound by construction (old 4x4: 128 vs 96+latency).
//  - A read from GLOBAL (uniform across the 16 lanes of a row group ->
//    broadcast transactions, ~512B/wave-iter; 8KB active slice L1-resident).
//    srow staging and its barrier deleted. LDS = W only (64KB) -> 2 blocks/CU.
//  - Ping-pong A prefetch (aA/aB), all array indices compile-time (rule #20).
//  - `#pragma unroll 1` on K-loop retained (round-3 spill lesson).
// ---------------------------------------------------------------------------
__global__ __launch_bounds__(256, 2)
void embw_gemm(const float* __restrict__ emb,
               const float* __restrict__ W,
               float* __restrict__ embW,
               int nrows)
{
    __shared__ float sW[D * D];      // 64 KB

    // stage W (coalesced float4)
    for (int idx = threadIdx.x; idx < D * D / 4; idx += 256) {
        reinterpret_cast<float4*>(sW)[idx] =
            reinterpret_cast<const float4*>(W)[idx];
    }

    const int jg   = threadIdx.x & 15;   // col group: cols 8*jg .. 8*jg+7
    const int rg   = threadIdx.x >> 4;   // row group: rows 8*rg .. 8*rg+7 (of 128)
    const int base = blockIdx.x * 128;
    const int row0 = base + rg * 8;

    __syncthreads();

    float acc[8][8];
#pragma unroll
    for (int r = 0; r < 8; ++r)
#pragma unroll
        for (int c = 0; c < 8; ++c) acc[r][c] = 0.f;

    // per-row global base pointers (clamped; OOB rows redundantly load row N-1)
    const float* ab[8];
#pragma unroll
    for (int r = 0; r < 8; ++r) {
        int rr = row0 + r;
        rr = rr < nrows ? rr : nrows - 1;
        ab[r] = emb + (size_t)rr * D;
    }

    const float* wbase = sW + jg * 8;

    float4 aA[8], aB[8];
#pragma unroll
    for (int r = 0; r < 8; ++r)
        aA[r] = *reinterpret_cast<const float4*>(ab[r]);

#pragma unroll 1
    for (int i0 = 0; i0 < D; i0 += 8) {
        // prefetch k = i0+4 .. i0+7
#pragma unroll
        for (int r = 0; r < 8; ++r)
            aB[r] = *reinterpret_cast<const float4*>(ab[r] + i0 + 4);

        // compute k = i0 .. i0+3 with aA
#pragma unroll
        for (int u = 0; u < 4; ++u) {
            const float4 wlo = *reinterpret_cast<const float4*>(&wbase[(i0 + u) * D]);
            const float4 whi = *reinterpret_cast<const float4*>(&wbase[(i0 + u) * D + 4]);
#pragma unroll
            for (int r = 0; r < 8; ++r) {
                float e = (u == 0) ? aA[r].x : (u == 1) ? aA[r].y
                        : (u == 2) ? aA[r].z : aA[r].w;
                acc[r][0] = fmaf(e, wlo.x, acc[r][0]);
                acc[r][1] = fmaf(e, wlo.y, acc[r][1]);
                acc[r][2] = fmaf(e, wlo.z, acc[r][2]);
                acc[r][3] = fmaf(e, wlo.w, acc[r][3]);
                acc[r][4] = fmaf(e, whi.x, acc[r][4]);
                acc[r][5] = fmaf(e, whi.y, acc[r][5]);
                acc[r][6] = fmaf(e, whi.z, acc[r][6]);
                acc[r][7] = fmaf(e, whi.w, acc[r][7]);
            }
        }

        // prefetch next iteration's first half (k = i0+8 .. i0+11), guarded
        if (i0 + 8 < D) {
#pragma unroll
            for (int r = 0; r < 8; ++r)
                aA[r] = *reinterpret_cast<const float4*>(ab[r] + i0 + 8);
        }

        // compute k = i0+4 .. i0+7 with aB
#pragma unroll
        for (int u = 0; u < 4; ++u) {
            const float4 wlo = *reinterpret_cast<const float4*>(&wbase[(i0 + 4 + u) * D]);
            const float4 whi = *reinterpret_cast<const float4*>(&wbase[(i0 + 4 + u) * D + 4]);
#pragma unroll
            for (int r = 0; r < 8; ++r) {
                float e = (u == 0) ? aB[r].x : (u == 1) ? aB[r].y
                        : (u == 2) ? aB[r].z : aB[r].w;
                acc[r][0] = fmaf(e, wlo.x, acc[r][0]);
                acc[r][1] = fmaf(e, wlo.y, acc[r][1]);
                acc[r][2] = fmaf(e, wlo.z, acc[r][2]);
                acc[r][3] = fmaf(e, wlo.w, acc[r][3]);
                acc[r][4] = fmaf(e, whi.x, acc[r][4]);
                acc[r][5] = fmaf(e, whi.y, acc[r][5]);
                acc[r][6] = fmaf(e, whi.z, acc[r][6]);
                acc[r][7] = fmaf(e, whi.w, acc[r][7]);
            }
        }
    }

#pragma unroll
    for (int r = 0; r < 8; ++r) {
        int rr = row0 + r;
        if (rr < nrows) {
            float4* dst = reinterpret_cast<float4*>(embW + (size_t)rr * D + jg * 8);
            dst[0] = make_float4(acc[r][0], acc[r][1], acc[r][2], acc[r][3]);
            dst[1] = make_float4(acc[r][4], acc[r][5], acc[r][6], acc[r][7]);
        }
    }
}

// ---------------------------------------------------------------------------
// Shared device helpers for the pair phase
// ---------------------------------------------------------------------------
__device__ __forceinline__ void block_softmaxes(const float* distance_att,
                                                const float* metapath_att,
                                                float* s_dis, float* s_mp,
                                                int tid)
{
    if (tid == 0) {
        float v[E];
        float mx = -1e30f;
        for (int i = 0; i < E; ++i) { v[i] = distance_att[i]; mx = fmaxf(mx, v[i]); }
        float sum = 0.f;
        for (int i = 0; i < E; ++i) { v[i] = expf(v[i] - mx); sum += v[i]; }
        for (int i = 0; i < E; ++i) s_dis[i] = v[i] / sum;

        float w[MPT];
        mx = -1e30f;
        for (int i = 0; i < MPT; ++i) { w[i] = metapath_att[i]; mx = fmaxf(mx, w[i]); }
        sum = 0.f;
        for (int i = 0; i < MPT; ++i) { w[i] = expf(w[i] - mx); sum += w[i]; }
        for (int i = 0; i < MPT; ++i) s_mp[i] = w[i] / sum;
    }
}

// Decode a task id into (src, dst, slot, weight).
__device__ __forceinline__ void decode_task(
    int task, int b, int s, int t, float tt, float dss, float dsdt,
    const float* __restrict__ delta,
    const float* __restrict__ s_dis, const float* __restrict__ s_mp,
    const int* __restrict__ mp_src, const int* __restrict__ mp_dst,
    const float* __restrict__ mp_time, const int* __restrict__ mp_dist,
    const int* __restrict__ mp_type,
    const int* __restrict__ neg_node,
    const int* __restrict__ neg_mp_src, const int* __restrict__ neg_mp_dst,
    const float* __restrict__ neg_mp_time, const int* __restrict__ neg_mp_dist,
    const int* __restrict__ neg_mp_type,
    int& srcn, int& dstn, int& slot, float& wgt)
{
    if (task == 0) {
        srcn = s; dstn = t; slot = 0; wgt = 1.f;
    } else if (task <= MXE) {
        int pe = task - 1;          // pe = m*E + e
        int m  = pe / E;
        int idx = b * MXE + pe;
        srcn = mp_src[idx];
        dstn = mp_dst[idx];
        slot = 0;
        float dec = expf(-dsdt * fabsf(tt - mp_time[idx]));
        wgt = s_dis[mp_dist[idx]] * dec * s_mp[mp_type[b * M + m]];
    } else if (task <= MXE + Q) {
        int q = task - 1 - MXE;
        srcn = s;                   // bilinear src is s (asymmetric!)
        dstn = neg_node[b * Q + q];
        slot = 1 + q;
        wgt  = 1.f;
    } else {
        int ne  = task - 1 - MXE - Q;   // ne = q*MXE + m*E + e
        int q   = ne / MXE;
        int rem = ne - q * MXE;
        int m   = rem / E;
        int idx = (b * Q + q) * MXE + rem;
        srcn = neg_mp_src[idx];
        dstn = neg_mp_dst[idx];
        slot = 1 + q;
        float dneg = delta[neg_node[b * Q + q]];
        float dec  = expf(-(dss * dneg) * fabsf(tt - neg_mp_time[idx]));
        wgt = s_dis[neg_mp_dist[idx]] * dec * s_mp[neg_mp_type[(b * Q + q) * M + m]];
    }
}

__device__ __forceinline__ void epilogue(const float* slots, float* out, int b)
{
    const float eps = 1e-6f;
    float p = slots[0];
    float loss = -logf(1.f / (1.f + expf(-p)) + eps);
#pragma unroll
    for (int q = 0; q < Q; ++q) {
        float v = slots[1 + q];
        loss -= logf(1.f / (1.f + expf(v)) + eps);   // log(sigmoid(-v)+eps)
    }
    out[b] = loss;
}

// ---------------------------------------------------------------------------
// Kernel 2: per-b weighted-dot accumulation + log-sigmoid epilogue.
// One block (512 threads = 32 x 16-lane subgroups) per b.
// (Unchanged for clean attribution; its counters land next successful round.)
// ---------------------------------------------------------------------------
__global__ __launch_bounds__(512)
void pair_kernel(const float* __restrict__ emb,
                 const float* __restrict__ embW,
                 const float* __restrict__ delta,
                 const float* __restrict__ distance_att,
                 const float* __restrict__ metapath_att,
                 const int*   __restrict__ s_node,
                 const int*   __restrict__ t_node,
                 const float* __restrict__ s_t_time,
                 const int*   __restrict__ mp_src,
                 const int*   __restrict__ mp_dst,
                 const float* __restrict__ mp_time,
                 const int*   __restrict__ mp_dist,
                 const int*   __restrict__ mp_type,
                 const int*   __restrict__ neg_node,
                 const int*   __restrict__ neg_mp_src,
                 const int*   __restrict__ neg_mp_dst,
                 const float* __restrict__ neg_mp_time,
                 const int*   __restrict__ neg_mp_dist,
                 const int*   __restrict__ neg_mp_type,
                 float* __restrict__ out)
{
    __shared__ float slots[1 + Q];
    __shared__ float s_dis[E];
    __shared__ float s_mp[MPT];

    const int b   = blockIdx.x;
    const int tid = threadIdx.x;

    if (tid < 1 + Q) slots[tid] = 0.f;
    block_softmaxes(distance_att, metapath_att, s_dis, s_mp, tid);
    __syncthreads();

    const int   s    = s_node[b];
    const int   t    = t_node[b];
    const float tt   = s_t_time[b];
    const float dss  = delta[s];
    const float dsdt = dss * delta[t];

    const int sg = tid >> 4;   // subgroup 0..31
    const int ln = tid & 15;   // lane in subgroup

    for (int task = sg; task < TASKS; task += 32) {
        int srcn, dstn, slot;
        float wgt;
        decode_task(task, b, s, t, tt, dss, dsdt, delta, s_dis, s_mp,
                    mp_src, mp_dst, mp_time, mp_dist, mp_type,
                    neg_node, neg_mp_src, neg_mp_dst, neg_mp_time,
                    neg_mp_dist, neg_mp_type, srcn, dstn, slot, wgt);

        // 128-dim dot: 16 lanes x 8 elements (2x float4 each side)
        const float4* pa = reinterpret_cast<const float4*>(embW + (size_t)srcn * D + ln * 8);
        const float4* pb = reinterpret_cast<const float4*>(emb  + (size_t)dstn * D + ln * 8);
        float4 a0 = pa[0], a1 = pa[1];
        float4 b0 = pb[0], b1 = pb[1];
        float d = a0.x * b0.x + a0.y * b0.y + a0.z * b0.z + a0.w * b0.w
                + a1.x * b1.x + a1.y * b1.y + a1.z * b1.z + a1.w * b1.w;
        d += __shfl_xor(d, 8);
        d += __shfl_xor(d, 4);
        d += __shfl_xor(d, 2);
        d += __shfl_xor(d, 1);
        if (ln == 0) atomicAdd(&slots[slot], d * wgt);
    }
    __syncthreads();

    if (tid == 0) epilogue(slots, out, b);
}

// ---------------------------------------------------------------------------
// Fallback (workspace too small): one wave per task; computes v = emb[src]@W
// on the fly. One block (512 threads = 8 waves) per b. (Not used when ws_size
// is sufficient — round-5 counters confirmed the fast path runs.)
// ---------------------------------------------------------------------------
__global__ __launch_bounds__(512)
void pair_direct(const float* __restrict__ emb,
                 const float* __restrict__ W,
                 const float* __restrict__ delta,
                 const float* __restrict__ distance_att,
                 const float* __restrict__ metapath_att,
                 const int*   __restrict__ s_node,
                 const int*   __restrict__ t_node,
                 const float* __restrict__ s_t_time,
                 const int*   __restrict__ mp_src,
                 const int*   __restrict__ mp_dst,
                 const float* __restrict__ mp_time,
                 const int*   __restrict__ mp_dist,
                 const int*   __restrict__ mp_type,
                 const int*   __restrict__ neg_node,
                 const int*   __restrict__ neg_mp_src,
                 const int*   __restrict__ neg_mp_dst,
                 const float* __restrict__ neg_mp_time,
                 const int*   __restrict__ neg_mp_dist,
                 const int*   __restrict__ neg_mp_type,
                 float* __restrict__ out)
{
    __shared__ float slots[1 + Q];
    __shared__ float s_dis[E];
    __shared__ float s_mp[MPT];

    const int b   = blockIdx.x;
    const int tid = threadIdx.x;

    if (tid < 1 + Q) slots[tid] = 0.f;
    block_softmaxes(distance_att, metapath_att, s_dis, s_mp, tid);
    __syncthreads();

    const int   s    = s_node[b];
    const int   t    = t_node[b];
    const float tt   = s_t_time[b];
    const float dss  = delta[s];
    const float dsdt = dss * delta[t];

    const int wave = tid >> 6;   // 0..7
    const int ln   = tid & 63;   // lane in wave

    for (int task = wave; task < TASKS; task += 8) {
        int srcn, dstn, slot;
        float wgt;
        decode_task(task, b, s, t, tt, dss, dsdt, delta, s_dis, s_mp,
                    mp_src, mp_dst, mp_time, mp_dist, mp_type,
                    neg_node, neg_mp_src, neg_mp_dst, neg_mp_time,
                    neg_mp_dist, neg_mp_type, srcn, dstn, slot, wgt);

        // v[j] = sum_i emb[src][i] * W[i][j]; lane ln owns cols ln and ln+64
        const float* erow = emb + (size_t)srcn * D;
        float v0 = 0.f, v1 = 0.f;
#pragma unroll 1
        for (int i = 0; i < D; ++i) {
            float a = erow[i];                    // broadcast across wave
            v0 = fmaf(a, W[i * D + ln], v0);      // coalesced 64-lane read
            v1 = fmaf(a, W[i * D + ln + 64], v1);
        }
        const float* drow = emb + (size_t)dstn * D;
        float d = v0 * drow[ln] + v1 * drow[ln + 64];
        // full 64-lane reduce
        d += __shfl_xor(d, 32);
        d += __shfl_xor(d, 16);
        d += __shfl_xor(d, 8);
        d += __shfl_xor(d, 4);
        d += __shfl_xor(d, 2);
        d += __shfl_xor(d, 1);
        if (ln == 0) atomicAdd(&slots[slot], d * wgt);
    }
    __syncthreads();

    if (tid == 0) epilogue(slots, out, b);
}

// ---------------------------------------------------------------------------
extern "C" void kernel_launch(void* const* d_in, const int* in_sizes, int n_in,
                              void* d_out, int out_size, void* d_ws, size_t ws_size,
                              hipStream_t stream)
{
    const float* emb          = (const float*)d_in[0];
    const float* delta        = (const float*)d_in[1];
    const float* W            = (const float*)d_in[2];
    const float* distance_att = (const float*)d_in[3];
    const float* metapath_att = (const float*)d_in[4];
    const int*   s_node       = (const int*)d_in[5];
    const int*   t_node       = (const int*)d_in[6];
    const float* s_t_time     = (const float*)d_in[7];
    const int*   mp_src       = (const int*)d_in[8];
    const int*   mp_dst       = (const int*)d_in[9];
    const float* mp_time      = (const float*)d_in[10];
    const int*   mp_dist      = (const int*)d_in[11];
    const int*   mp_type      = (const int*)d_in[12];
    const int*   neg_node     = (const int*)d_in[13];
    const int*   neg_mp_src   = (const int*)d_in[14];
    const int*   neg_mp_dst   = (const int*)d_in[15];
    const float* neg_mp_time  = (const float*)d_in[16];
    const int*   neg_mp_dist  = (const int*)d_in[17];
    const int*   neg_mp_type  = (const int*)d_in[18];

    const int N = in_sizes[1];       // delta has N elements
    const int B = in_sizes[5];       // s_node has B elements

    const size_t need = (size_t)N * D * sizeof(float);   // 51.2 MB

    if (ws_size >= need) {
        // Fast path: precompute embW = emb @ W, then gather-dots.
        float* embW = (float*)d_ws;
        int blocks1 = (N + 127) / 128;
        embw_gemm<<<blocks1, 256, 0, stream>>>(emb, W, embW, N);
        pair_kernel<<<B, 512, 0, stream>>>(emb, embW, delta,
                                           distance_att, metapath_att,
                                           s_node, t_node, s_t_time,
                                           mp_src, mp_dst, mp_time, mp_dist, mp_type,
                                           neg_node, neg_mp_src, neg_mp_dst,
                                           neg_mp_time, neg_mp_dist, neg_mp_type,
                                           (float*)d_out);
    } else {
        // Fallback: direct evaluation, no workspace needed.
        pair_direct<<<B, 512, 0, stream>>>(emb, W, delta,
                                           distance_att, metapath_att,
                                           s_node, t_node, s_t_time,
                                           mp_src, mp_dst, mp_time, mp_dist, mp_type,
                                           neg_node, neg_mp_src, neg_mp_dst,
                                           neg_mp_time, neg_mp_dist, neg_mp_type,
                                           (float*)d_out);
    }
}

// Round 11
// 184.900 us; speedup vs baseline: 11.8799x; 1.0052x over previous
//
#include <hip/hip_runtime.h>
#include <hip/hip_bf16.h>
#include <math.h>

// Problem constants (match reference): N=100000, D=128, B=512, M=4, E=10, Q=5, MPT=8
constexpr int D   = 128;
constexpr int M   = 4;
constexpr int E   = 10;
constexpr int Q   = 5;
constexpr int MPT = 8;
constexpr int MXE = M * E;                       // 40
constexpr int TASKS = 1 + MXE + Q + Q * MXE;     // 246 weighted dots per b

// ---------------------------------------------------------------------------
// Kernel 1: embW = emb @ W  (fp32 vector FMA; no fp32 MFMA on CDNA4)
//
// ROUND-9 FIX (resubmitted unmeasured, r10 broker timeout): r9 counters
// showed 3.2M LDS bank conflicts (r4: 0) — the 8x8 version read W as 2
// float4 at byte stride 32 across 16 lanes -> only 16/32 banks touched,
// ~4-way serialization -> LDS-pipe still the limit (VALUBusy 35%, dur
// unchanged 76us). Fix: lane jg owns SPLIT columns [4jg,4jg+4) u
// [64+4jg,64+4jg+4) so both W reads are 16-lane stride-16B contiguous 256B
// spans = 2 addr/bank = conflict-free (m136; r4 pattern). Everything else
// (8x8 tiles, global-A broadcast, ping-pong prefetch, unroll-1 K-loop)
// unchanged from r9.
// ---------------------------------------------------------------------------
__global__ __launch_bounds__(256, 2)
void embw_gemm(const float* __restrict__ emb,
               const float* __restrict__ W,
               float* __restrict__ embW,
               int nrows)
{
    __shared__ float sW[D * D];      // 64 KB

    // stage W (coalesced float4)
    for (int idx = threadIdx.x; idx < D * D / 4; idx += 256) {
        reinterpret_cast<float4*>(sW)[idx] =
            reinterpret_cast<const float4*>(W)[idx];
    }

    const int jg   = threadIdx.x & 15;   // col group: cols [4jg,4jg+4) u [64+4jg, ...)
    const int rg   = threadIdx.x >> 4;   // row group: rows 8*rg .. 8*rg+7 (of 128)
    const int base = blockIdx.x * 128;
    const int row0 = base + rg * 8;

    __syncthreads();

    float acc[8][8];
#pragma unroll
    for (int r = 0; r < 8; ++r)
#pragma unroll
        for (int c = 0; c < 8; ++c) acc[r][c] = 0.f;

    // per-row global base pointers (clamped; OOB rows redundantly load row N-1)
    const float* ab[8];
#pragma unroll
    for (int r = 0; r < 8; ++r) {
        int rr = row0 + r;
        rr = rr < nrows ? rr : nrows - 1;
        ab[r] = emb + (size_t)rr * D;
    }

    const float* wlo_base = sW + jg * 4;        // cols 4jg..4jg+3
    const float* whi_base = sW + 64 + jg * 4;   // cols 64+4jg..64+4jg+3

    float4 aA[8], aB[8];
#pragma unroll
    for (int r = 0; r < 8; ++r)
        aA[r] = *reinterpret_cast<const float4*>(ab[r]);

#pragma unroll 1
    for (int i0 = 0; i0 < D; i0 += 8) {
        // prefetch k = i0+4 .. i0+7
#pragma unroll
        for (int r = 0; r < 8; ++r)
            aB[r] = *reinterpret_cast<const float4*>(ab[r] + i0 + 4);

        // compute k = i0 .. i0+3 with aA
#pragma unroll
        for (int u = 0; u < 4; ++u) {
            const float4 wlo = *reinterpret_cast<const float4*>(&wlo_base[(i0 + u) * D]);
            const float4 whi = *reinterpret_cast<const float4*>(&whi_base[(i0 + u) * D]);
#pragma unroll
            for (int r = 0; r < 8; ++r) {
                float e = (u == 0) ? aA[r].x : (u == 1) ? aA[r].y
                        : (u == 2) ? aA[r].z : aA[r].w;
                acc[r][0] = fmaf(e, wlo.x, acc[r][0]);
                acc[r][1] = fmaf(e, wlo.y, acc[r][1]);
                acc[r][2] = fmaf(e, wlo.z, acc[r][2]);
                acc[r][3] = fmaf(e, wlo.w, acc[r][3]);
                acc[r][4] = fmaf(e, whi.x, acc[r][4]);
                acc[r][5] = fmaf(e, whi.y, acc[r][5]);
                acc[r][6] = fmaf(e, whi.z, acc[r][6]);
                acc[r][7] = fmaf(e, whi.w, acc[r][7]);
            }
        }

        // prefetch next iteration's first half (k = i0+8 .. i0+11), guarded
        if (i0 + 8 < D) {
#pragma unroll
            for (int r = 0; r < 8; ++r)
                aA[r] = *reinterpret_cast<const float4*>(ab[r] + i0 + 8);
        }

        // compute k = i0+4 .. i0+7 with aB
#pragma unroll
        for (int u = 0; u < 4; ++u) {
            const float4 wlo = *reinterpret_cast<const float4*>(&wlo_base[(i0 + 4 + u) * D]);
            const float4 whi = *reinterpret_cast<const float4*>(&whi_base[(i0 + 4 + u) * D]);
#pragma unroll
            for (int r = 0; r < 8; ++r) {
                float e = (u == 0) ? aB[r].x : (u == 1) ? aB[r].y
                        : (u == 2) ? aB[r].z : aB[r].w;
                acc[r][0] = fmaf(e, wlo.x, acc[r][0]);
                acc[r][1] = fmaf(e, wlo.y, acc[r][1]);
                acc[r][2] = fmaf(e, wlo.z, acc[r][2]);
                acc[r][3] = fmaf(e, wlo.w, acc[r][3]);
                acc[r][4] = fmaf(e, whi.x, acc[r][4]);
                acc[r][5] = fmaf(e, whi.y, acc[r][5]);
                acc[r][6] = fmaf(e, whi.z, acc[r][6]);
                acc[r][7] = fmaf(e, whi.w, acc[r][7]);
            }
        }
    }

#pragma unroll
    for (int r = 0; r < 8; ++r) {
        int rr = row0 + r;
        if (rr < nrows) {
            float* rowp = embW + (size_t)rr * D;
            *reinterpret_cast<float4*>(rowp + jg * 4) =
                make_float4(acc[r][0], acc[r][1], acc[r][2], acc[r][3]);
            *reinterpret_cast<float4*>(rowp + 64 + jg * 4) =
                make_float4(acc[r][4], acc[r][5], acc[r][6], acc[r][7]);
        }
    }
}

// ---------------------------------------------------------------------------
// Shared device helpers for the pair phase
// ---------------------------------------------------------------------------
__device__ __forceinline__ void block_softmaxes(const float* distance_att,
                                                const float* metapath_att,
                                                float* s_dis, float* s_mp,
                                                int tid)
{
    if (tid == 0) {
        float v[E];
        float mx = -1e30f;
        for (int i = 0; i < E; ++i) { v[i] = distance_att[i]; mx = fmaxf(mx, v[i]); }
        float sum = 0.f;
        for (int i = 0; i < E; ++i) { v[i] = expf(v[i] - mx); sum += v[i]; }
        for (int i = 0; i < E; ++i) s_dis[i] = v[i] / sum;

        float w[MPT];
        mx = -1e30f;
        for (int i = 0; i < MPT; ++i) { w[i] = metapath_att[i]; mx = fmaxf(mx, w[i]); }
        sum = 0.f;
        for (int i = 0; i < MPT; ++i) { w[i] = expf(w[i] - mx); sum += w[i]; }
        for (int i = 0; i < MPT; ++i) s_mp[i] = w[i] / sum;
    }
}

// Decode a task id into (src, dst, slot, weight).
__device__ __forceinline__ void decode_task(
    int task, int b, int s, int t, float tt, float dss, float dsdt,
    const float* __restrict__ delta,
    const float* __restrict__ s_dis, const float* __restrict__ s_mp,
    const int* __restrict__ mp_src, const int* __restrict__ mp_dst,
    const float* __restrict__ mp_time, const int* __restrict__ mp_dist,
    const int* __restrict__ mp_type,
    const int* __restrict__ neg_node,
    const int* __restrict__ neg_mp_src, const int* __restrict__ neg_mp_dst,
    const float* __restrict__ neg_mp_time, const int* __restrict__ neg_mp_dist,
    const int* __restrict__ neg_mp_type,
    int& srcn, int& dstn, int& slot, float& wgt)
{
    if (task == 0) {
        srcn = s; dstn = t; slot = 0; wgt = 1.f;
    } else if (task <= MXE) {
        int pe = task - 1;          // pe = m*E + e
        int m  = pe / E;
        int idx = b * MXE + pe;
        srcn = mp_src[idx];
        dstn = mp_dst[idx];
        slot = 0;
        float dec = expf(-dsdt * fabsf(tt - mp_time[idx]));
        wgt = s_dis[mp_dist[idx]] * dec * s_mp[mp_type[b * M + m]];
    } else if (task <= MXE + Q) {
        int q = task - 1 - MXE;
        srcn = s;                   // bilinear src is s (asymmetric!)
        dstn = neg_node[b * Q + q];
        slot = 1 + q;
        wgt  = 1.f;
    } else {
        int ne  = task - 1 - MXE - Q;   // ne = q*MXE + m*E + e
        int q   = ne / MXE;
        int rem = ne - q * MXE;
        int m   = rem / E;
        int idx = (b * Q + q) * MXE + rem;
        srcn = neg_mp_src[idx];
        dstn = neg_mp_dst[idx];
        slot = 1 + q;
        float dneg = delta[neg_node[b * Q + q]];
        float dec  = expf(-(dss * dneg) * fabsf(tt - neg_mp_time[idx]));
        wgt = s_dis[neg_mp_dist[idx]] * dec * s_mp[neg_mp_type[(b * Q + q) * M + m]];
    }
}

__device__ __forceinline__ void epilogue(const float* slots, float* out, int b)
{
    const float eps = 1e-6f;
    float p = slots[0];
    float loss = -logf(1.f / (1.f + expf(-p)) + eps);
#pragma unroll
    for (int q = 0; q < Q; ++q) {
        float v = slots[1 + q];
        loss -= logf(1.f / (1.f + expf(v)) + eps);   // log(sigmoid(-v)+eps)
    }
    out[b] = loss;
}

// ---------------------------------------------------------------------------
// Kernel 2: per-b weighted-dot accumulation + log-sigmoid epilogue.
//
// ROUND-9 CHANGE (resubmitted unmeasured): block 512 -> 1024 threads
// (64 x 16-lane subgroups). Pair phase is latency-bound gathers; 512-thr
// blocks gave 7.7 serial task-rounds per subgroup. 1024 thr -> 3.85 rounds,
// 2 blocks/CU -> full 32 waves/CU occupancy.
// ---------------------------------------------------------------------------
__global__ __launch_bounds__(1024)
void pair_kernel(const float* __restrict__ emb,
                 const float* __restrict__ embW,
                 const float* __restrict__ delta,
                 const float* __restrict__ distance_att,
                 const float* __restrict__ metapath_att,
                 const int*   __restrict__ s_node,
                 const int*   __restrict__ t_node,
                 const float* __restrict__ s_t_time,
                 const int*   __restrict__ mp_src,
                 const int*   __restrict__ mp_dst,
                 const float* __restrict__ mp_time,
                 const int*   __restrict__ mp_dist,
                 const int*   __restrict__ mp_type,
                 const int*   __restrict__ neg_node,
                 const int*   __restrict__ neg_mp_src,
                 const int*   __restrict__ neg_mp_dst,
                 const float* __restrict__ neg_mp_time,
                 const int*   __restrict__ neg_mp_dist,
                 const int*   __restrict__ neg_mp_type,
                 float* __restrict__ out)
{
    __shared__ float slots[1 + Q];
    __shared__ float s_dis[E];
    __shared__ float s_mp[MPT];

    const int b   = blockIdx.x;
    const int tid = threadIdx.x;

    if (tid < 1 + Q) slots[tid] = 0.f;
    block_softmaxes(distance_att, metapath_att, s_dis, s_mp, tid);
    __syncthreads();

    const int   s    = s_node[b];
    const int   t    = t_node[b];
    const float tt   = s_t_time[b];
    const float dss  = delta[s];
    const float dsdt = dss * delta[t];

    const int sg = tid >> 4;   // subgroup 0..63
    const int ln = tid & 15;   // lane in subgroup

    for (int task = sg; task < TASKS; task += 64) {
        int srcn, dstn, slot;
        float wgt;
        decode_task(task, b, s, t, tt, dss, dsdt, delta, s_dis, s_mp,
                    mp_src, mp_dst, mp_time, mp_dist, mp_type,
                    neg_node, neg_mp_src, neg_mp_dst, neg_mp_time,
                    neg_mp_dist, neg_mp_type, srcn, dstn, slot, wgt);

        // 128-dim dot: 16 lanes x 8 elements (2x float4 each side)
        const float4* pa = reinterpret_cast<const float4*>(embW + (size_t)srcn * D + ln * 8);
        const float4* pb = reinterpret_cast<const float4*>(emb  + (size_t)dstn * D + ln * 8);
        float4 a0 = pa[0], a1 = pa[1];
        float4 b0 = pb[0], b1 = pb[1];
        float d = a0.x * b0.x + a0.y * b0.y + a0.z * b0.z + a0.w * b0.w
                + a1.x * b1.x + a1.y * b1.y + a1.z * b1.z + a1.w * b1.w;
        d += __shfl_xor(d, 8);
        d += __shfl_xor(d, 4);
        d += __shfl_xor(d, 2);
        d += __shfl_xor(d, 1);
        if (ln == 0) atomicAdd(&slots[slot], d * wgt);
    }
    __syncthreads();

    if (tid == 0) epilogue(slots, out, b);
}

// ---------------------------------------------------------------------------
// Fallback (workspace too small): one wave per task; computes v = emb[src]@W
// on the fly. One block (512 threads = 8 waves) per b. (Not used when ws_size
// is sufficient — counters confirm the fast path runs.)
// ---------------------------------------------------------------------------
__global__ __launch_bounds__(512)
void pair_direct(const float* __restrict__ emb,
                 const float* __restrict__ W,
                 const float* __restrict__ delta,
                 const float* __restrict__ distance_att,
                 const float* __restrict__ metapath_att,
                 const int*   __restrict__ s_node,
                 const int*   __restrict__ t_node,
                 const float* __restrict__ s_t_time,
                 const int*   __restrict__ mp_src,
                 const int*   __restrict__ mp_dst,
                 const float* __restrict__ mp_time,
                 const int*   __restrict__ mp_dist,
                 const int*   __restrict__ mp_type,
                 const int*   __restrict__ neg_node,
                 const int*   __restrict__ neg_mp_src,
                 const int*   __restrict__ neg_mp_dst,
                 const float* __restrict__ neg_mp_time,
                 const int*   __restrict__ neg_mp_dist,
                 const int*   __restrict__ neg_mp_type,
                 float* __restrict__ out)
{
    __shared__ float slots[1 + Q];
    __shared__ float s_dis[E];
    __shared__ float s_mp[MPT];

    const int b   = blockIdx.x;
    const int tid = threadIdx.x;

    if (tid < 1 + Q) slots[tid] = 0.f;
    block_softmaxes(distance_att, metapath_att, s_dis, s_mp, tid);
    __syncthreads();

    const int   s    = s_node[b];
    const int   t    = t_node[b];
    const float tt   = s_t_time[b];
    const float dss  = delta[s];
    const float dsdt = dss * delta[t];

    const int wave = tid >> 6;   // 0..7
    const int ln   = tid & 63;   // lane in wave

    for (int task = wave; task < TASKS; task += 8) {
        int srcn, dstn, slot;
        float wgt;
        decode_task(task, b, s, t, tt, dss, dsdt, delta, s_dis, s_mp,
                    mp_src, mp_dst, mp_time, mp_dist, mp_type,
                    neg_node, neg_mp_src, neg_mp_dst, neg_mp_time,
                    neg_mp_dist, neg_mp_type, srcn, dstn, slot, wgt);

        // v[j] = sum_i emb[src][i] * W[i][j]; lane ln owns cols ln and ln+64
        const float* erow = emb + (size_t)srcn * D;
        float v0 = 0.f, v1 = 0.f;
#pragma unroll 1
        for (int i = 0; i < D; ++i) {
            float a = erow[i];                    // broadcast across wave
            v0 = fmaf(a, W[i * D + ln], v0);      // coalesced 64-lane read
            v1 = fmaf(a, W[i * D + ln + 64], v1);
        }
        const float* drow = emb + (size_t)dstn * D;
        float d = v0 * drow[ln] + v1 * drow[ln + 64];
        // full 64-lane reduce
        d += __shfl_xor(d, 32);
        d += __shfl_xor(d, 16);
        d += __shfl_xor(d, 8);
        d += __shfl_xor(d, 4);
        d += __shfl_xor(d, 2);
        d += __shfl_xor(d, 1);
        if (ln == 0) atomicAdd(&slots[slot], d * wgt);
    }
    __syncthreads();

    if (tid == 0) epilogue(slots, out, b);
}

// ---------------------------------------------------------------------------
extern "C" void kernel_launch(void* const* d_in, const int* in_sizes, int n_in,
                              void* d_out, int out_size, void* d_ws, size_t ws_size,
                              hipStream_t stream)
{
    const float* emb          = (const float*)d_in[0];
    const float* delta        = (const float*)d_in[1];
    const float* W            = (const float*)d_in[2];
    const float* distance_att = (const float*)d_in[3];
    const float* metapath_att = (const float*)d_in[4];
    const int*   s_node       = (const int*)d_in[5];
    const int*   t_node       = (const int*)d_in[6];
    const float* s_t_time     = (const float*)d_in[7];
    const int*   mp_src       = (const int*)d_in[8];
    const int*   mp_dst       = (const int*)d_in[9];
    const float* mp_time      = (const float*)d_in[10];
    const int*   mp_dist      = (const int*)d_in[11];
    const int*   mp_type      = (const int*)d_in[12];
    const int*   neg_node     = (const int*)d_in[13];
    const int*   neg_mp_src   = (const int*)d_in[14];
    const int*   neg_mp_dst   = (const int*)d_in[15];
    const float* neg_mp_time  = (const float*)d_in[16];
    const int*   neg_mp_dist  = (const int*)d_in[17];
    const int*   neg_mp_type  = (const int*)d_in[18];

    const int N = in_sizes[1];       // delta has N elements
    const int B = in_sizes[5];       // s_node has B elements

    const size_t need = (size_t)N * D * sizeof(float);   // 51.2 MB

    if (ws_size >= need) {
        // Fast path: precompute embW = emb @ W, then gather-dots.
        float* embW = (float*)d_ws;
        int blocks1 = (N + 127) / 128;
        embw_gemm<<<blocks1, 256, 0, stream>>>(emb, W, embW, N);
        pair_kernel<<<B, 1024, 0, stream>>>(emb, embW, delta,
                                            distance_att, metapath_att,
                                            s_node, t_node, s_t_time,
                                            mp_src, mp_dst, mp_time, mp_dist, mp_type,
                                            neg_node, neg_mp_src, neg_mp_dst,
                                            neg_mp_time, neg_mp_dist, neg_mp_type,
                                            (float*)d_out);
    } else {
        // Fallback: direct evaluation, no workspace needed.
        pair_direct<<<B, 512, 0, stream>>>(emb, W, delta,
                                           distance_att, metapath_att,
                                           s_node, t_node, s_t_time,
                                           mp_src, mp_dst, mp_time, mp_dist, mp_type,
                                           neg_node, neg_mp_src, neg_mp_dst,
                                           neg_mp_time, neg_mp_dist, neg_mp_type,
                                           (float*)d_out);
    }
}

// Round 13
// 183.679 us; speedup vs baseline: 11.9588x; 1.0066x over previous
//
#include <hip/hip_runtime.h>
#include <hip/hip_bf16.h>
#include <math.h>

// Problem constants (match reference): N=100000, D=128, B=512, M=4, E=10, Q=5, MPT=8
constexpr int D   = 128;
constexpr int M   = 4;
constexpr int E   = 10;
constexpr int Q   = 5;
constexpr int MPT = 8;
constexpr int MXE = M * E;                       // 40
constexpr int TASKS = 1 + MXE + Q + Q * MXE;     // 246 weighted dots per b

// ---------------------------------------------------------------------------
// Kernel 1: embW = emb @ W  (fp32 vector FMA; no fp32 MFMA on CDNA4)
//
// ROUND-11 FIX (resubmitted unmeasured, r12 broker timeout): r11 counters:
// conflicts 3.2M->0 (split-column fix verified) but dur only 75->66us,
// VALUBusy 39%, Occupancy 14% (~1 wave/SIMD resident) -> latency-exposure,
// not pipe-throughput, is the limit. Fix: block 256->512 threads (8 waves/
// block, 256 rows/block): 2 waves/SIMD even at 1 block/CU, 4/SIMD at 2
// blocks/CU. Per-thread work unchanged (8x8 tile, split-column conflict-free
// W reads, global-A broadcast, ping-pong prefetch, unroll-1).
// ---------------------------------------------------------------------------
__global__ __launch_bounds__(512, 2)
void embw_gemm(const float* __restrict__ emb,
               const float* __restrict__ W,
               float* __restrict__ embW,
               int nrows)
{
    __shared__ float sW[D * D];      // 64 KB

    // stage W (coalesced float4)
    for (int idx = threadIdx.x; idx < D * D / 4; idx += 512) {
        reinterpret_cast<float4*>(sW)[idx] =
            reinterpret_cast<const float4*>(W)[idx];
    }

    const int jg   = threadIdx.x & 15;   // col group: cols [4jg,4jg+4) u [64+4jg,...)
    const int rg   = threadIdx.x >> 4;   // row group 0..31: rows 8*rg .. 8*rg+7 (of 256)
    const int base = blockIdx.x * 256;
    const int row0 = base + rg * 8;

    __syncthreads();

    float acc[8][8];
#pragma unroll
    for (int r = 0; r < 8; ++r)
#pragma unroll
        for (int c = 0; c < 8; ++c) acc[r][c] = 0.f;

    // per-row global base pointers (clamped; OOB rows redundantly load row N-1)
    const float* ab[8];
#pragma unroll
    for (int r = 0; r < 8; ++r) {
        int rr = row0 + r;
        rr = rr < nrows ? rr : nrows - 1;
        ab[r] = emb + (size_t)rr * D;
    }

    const float* wlo_base = sW + jg * 4;        // cols 4jg..4jg+3
    const float* whi_base = sW + 64 + jg * 4;   // cols 64+4jg..64+4jg+3

    float4 aA[8], aB[8];
#pragma unroll
    for (int r = 0; r < 8; ++r)
        aA[r] = *reinterpret_cast<const float4*>(ab[r]);

#pragma unroll 1
    for (int i0 = 0; i0 < D; i0 += 8) {
        // prefetch k = i0+4 .. i0+7
#pragma unroll
        for (int r = 0; r < 8; ++r)
            aB[r] = *reinterpret_cast<const float4*>(ab[r] + i0 + 4);

        // compute k = i0 .. i0+3 with aA
#pragma unroll
        for (int u = 0; u < 4; ++u) {
            const float4 wlo = *reinterpret_cast<const float4*>(&wlo_base[(i0 + u) * D]);
            const float4 whi = *reinterpret_cast<const float4*>(&whi_base[(i0 + u) * D]);
#pragma unroll
            for (int r = 0; r < 8; ++r) {
                float e = (u == 0) ? aA[r].x : (u == 1) ? aA[r].y
                        : (u == 2) ? aA[r].z : aA[r].w;
                acc[r][0] = fmaf(e, wlo.x, acc[r][0]);
                acc[r][1] = fmaf(e, wlo.y, acc[r][1]);
                acc[r][2] = fmaf(e, wlo.z, acc[r][2]);
                acc[r][3] = fmaf(e, wlo.w, acc[r][3]);
                acc[r][4] = fmaf(e, whi.x, acc[r][4]);
                acc[r][5] = fmaf(e, whi.y, acc[r][5]);
                acc[r][6] = fmaf(e, whi.z, acc[r][6]);
                acc[r][7] = fmaf(e, whi.w, acc[r][7]);
            }
        }

        // prefetch next iteration's first half (k = i0+8 .. i0+11), guarded
        if (i0 + 8 < D) {
#pragma unroll
            for (int r = 0; r < 8; ++r)
                aA[r] = *reinterpret_cast<const float4*>(ab[r] + i0 + 8);
        }

        // compute k = i0+4 .. i0+7 with aB
#pragma unroll
        for (int u = 0; u < 4; ++u) {
            const float4 wlo = *reinterpret_cast<const float4*>(&wlo_base[(i0 + 4 + u) * D]);
            const float4 whi = *reinterpret_cast<const float4*>(&whi_base[(i0 + 4 + u) * D]);
#pragma unroll
            for (int r = 0; r < 8; ++r) {
                float e = (u == 0) ? aB[r].x : (u == 1) ? aB[r].y
                        : (u == 2) ? aB[r].z : aB[r].w;
                acc[r][0] = fmaf(e, wlo.x, acc[r][0]);
                acc[r][1] = fmaf(e, wlo.y, acc[r][1]);
                acc[r][2] = fmaf(e, wlo.z, acc[r][2]);
                acc[r][3] = fmaf(e, wlo.w, acc[r][3]);
                acc[r][4] = fmaf(e, whi.x, acc[r][4]);
                acc[r][5] = fmaf(e, whi.y, acc[r][5]);
                acc[r][6] = fmaf(e, whi.z, acc[r][6]);
                acc[r][7] = fmaf(e, whi.w, acc[r][7]);
            }
        }
    }

#pragma unroll
    for (int r = 0; r < 8; ++r) {
        int rr = row0 + r;
        if (rr < nrows) {
            float* rowp = embW + (size_t)rr * D;
            *reinterpret_cast<float4*>(rowp + jg * 4) =
                make_float4(acc[r][0], acc[r][1], acc[r][2], acc[r][3]);
            *reinterpret_cast<float4*>(rowp + 64 + jg * 4) =
                make_float4(acc[r][4], acc[r][5], acc[r][6], acc[r][7]);
        }
    }
}

// ---------------------------------------------------------------------------
// Shared device helpers for the pair phase
// ---------------------------------------------------------------------------
__device__ __forceinline__ void block_softmaxes(const float* distance_att,
                                                const float* metapath_att,
                                                float* s_dis, float* s_mp,
                                                int tid)
{
    if (tid == 0) {
        float v[E];
        float mx = -1e30f;
        for (int i = 0; i < E; ++i) { v[i] = distance_att[i]; mx = fmaxf(mx, v[i]); }
        float sum = 0.f;
        for (int i = 0; i < E; ++i) { v[i] = expf(v[i] - mx); sum += v[i]; }
        for (int i = 0; i < E; ++i) s_dis[i] = v[i] / sum;

        float w[MPT];
        mx = -1e30f;
        for (int i = 0; i < MPT; ++i) { w[i] = metapath_att[i]; mx = fmaxf(mx, w[i]); }
        sum = 0.f;
        for (int i = 0; i < MPT; ++i) { w[i] = expf(w[i] - mx); sum += w[i]; }
        for (int i = 0; i < MPT; ++i) s_mp[i] = w[i] / sum;
    }
}

// Decode a task id into (src, dst, slot, weight).
__device__ __forceinline__ void decode_task(
    int task, int b, int s, int t, float tt, float dss, float dsdt,
    const float* __restrict__ delta,
    const float* __restrict__ s_dis, const float* __restrict__ s_mp,
    const int* __restrict__ mp_src, const int* __restrict__ mp_dst,
    const float* __restrict__ mp_time, const int* __restrict__ mp_dist,
    const int* __restrict__ mp_type,
    const int* __restrict__ neg_node,
    const int* __restrict__ neg_mp_src, const int* __restrict__ neg_mp_dst,
    const float* __restrict__ neg_mp_time, const int* __restrict__ neg_mp_dist,
    const int* __restrict__ neg_mp_type,
    int& srcn, int& dstn, int& slot, float& wgt)
{
    if (task == 0) {
        srcn = s; dstn = t; slot = 0; wgt = 1.f;
    } else if (task <= MXE) {
        int pe = task - 1;          // pe = m*E + e
        int m  = pe / E;
        int idx = b * MXE + pe;
        srcn = mp_src[idx];
        dstn = mp_dst[idx];
        slot = 0;
        float dec = expf(-dsdt * fabsf(tt - mp_time[idx]));
        wgt = s_dis[mp_dist[idx]] * dec * s_mp[mp_type[b * M + m]];
    } else if (task <= MXE + Q) {
        int q = task - 1 - MXE;
        srcn = s;                   // bilinear src is s (asymmetric!)
        dstn = neg_node[b * Q + q];
        slot = 1 + q;
        wgt  = 1.f;
    } else {
        int ne  = task - 1 - MXE - Q;   // ne = q*MXE + m*E + e
        int q   = ne / MXE;
        int rem = ne - q * MXE;
        int m   = rem / E;
        int idx = (b * Q + q) * MXE + rem;
        srcn = neg_mp_src[idx];
        dstn = neg_mp_dst[idx];
        slot = 1 + q;
        float dneg = delta[neg_node[b * Q + q]];
        float dec  = expf(-(dss * dneg) * fabsf(tt - neg_mp_time[idx]));
        wgt = s_dis[neg_mp_dist[idx]] * dec * s_mp[neg_mp_type[(b * Q + q) * M + m]];
    }
}

__device__ __forceinline__ void epilogue(const float* slots, float* out, int b)
{
    const float eps = 1e-6f;
    float p = slots[0];
    float loss = -logf(1.f / (1.f + expf(-p)) + eps);
#pragma unroll
    for (int q = 0; q < Q; ++q) {
        float v = slots[1 + q];
        loss -= logf(1.f / (1.f + expf(v)) + eps);   // log(sigmoid(-v)+eps)
    }
    out[b] = loss;
}

// ---------------------------------------------------------------------------
// Kernel 2: per-b weighted-dot accumulation + log-sigmoid epilogue.
// 1024 threads = 64 x 16-lane subgroups per b (r9 change, measured r11:
// not in top-5 -> < 63us; unchanged this round).
// ---------------------------------------------------------------------------
__global__ __launch_bounds__(1024)
void pair_kernel(const float* __restrict__ emb,
                 const float* __restrict__ embW,
                 const float* __restrict__ delta,
                 const float* __restrict__ distance_att,
                 const float* __restrict__ metapath_att,
                 const int*   __restrict__ s_node,
                 const int*   __restrict__ t_node,
                 const float* __restrict__ s_t_time,
                 const int*   __restrict__ mp_src,
                 const int*   __restrict__ mp_dst,
                 const float* __restrict__ mp_time,
                 const int*   __restrict__ mp_dist,
                 const int*   __restrict__ mp_type,
                 const int*   __restrict__ neg_node,
                 const int*   __restrict__ neg_mp_src,
                 const int*   __restrict__ neg_mp_dst,
                 const float* __restrict__ neg_mp_time,
                 const int*   __restrict__ neg_mp_dist,
                 const int*   __restrict__ neg_mp_type,
                 float* __restrict__ out)
{
    __shared__ float slots[1 + Q];
    __shared__ float s_dis[E];
    __shared__ float s_mp[MPT];

    const int b   = blockIdx.x;
    const int tid = threadIdx.x;

    if (tid < 1 + Q) slots[tid] = 0.f;
    block_softmaxes(distance_att, metapath_att, s_dis, s_mp, tid);
    __syncthreads();

    const int   s    = s_node[b];
    const int   t    = t_node[b];
    const float tt   = s_t_time[b];
    const float dss  = delta[s];
    const float dsdt = dss * delta[t];

    const int sg = tid >> 4;   // subgroup 0..63
    const int ln = tid & 15;   // lane in subgroup

    for (int task = sg; task < TASKS; task += 64) {
        int srcn, dstn, slot;
        float wgt;
        decode_task(task, b, s, t, tt, dss, dsdt, delta, s_dis, s_mp,
                    mp_src, mp_dst, mp_time, mp_dist, mp_type,
                    neg_node, neg_mp_src, neg_mp_dst, neg_mp_time,
                    neg_mp_dist, neg_mp_type, srcn, dstn, slot, wgt);

        // 128-dim dot: 16 lanes x 8 elements (2x float4 each side)
        const float4* pa = reinterpret_cast<const float4*>(embW + (size_t)srcn * D + ln * 8);
        const float4* pb = reinterpret_cast<const float4*>(emb  + (size_t)dstn * D + ln * 8);
        float4 a0 = pa[0], a1 = pa[1];
        float4 b0 = pb[0], b1 = pb[1];
        float d = a0.x * b0.x + a0.y * b0.y + a0.z * b0.z + a0.w * b0.w
                + a1.x * b1.x + a1.y * b1.y + a1.z * b1.z + a1.w * b1.w;
        d += __shfl_xor(d, 8);
        d += __shfl_xor(d, 4);
        d += __shfl_xor(d, 2);
        d += __shfl_xor(d, 1);
        if (ln == 0) atomicAdd(&slots[slot], d * wgt);
    }
    __syncthreads();

    if (tid == 0) epilogue(slots, out, b);
}

// ---------------------------------------------------------------------------
// Fallback (workspace too small): one wave per task; computes v = emb[src]@W
// on the fly. One block (512 threads = 8 waves) per b. (Not used when ws_size
// is sufficient — counters confirm the fast path runs.)
// ---------------------------------------------------------------------------
__global__ __launch_bounds__(512)
void pair_direct(const float* __restrict__ emb,
                 const float* __restrict__ W,
                 const float* __restrict__ delta,
                 const float* __restrict__ distance_att,
                 const float* __restrict__ metapath_att,
                 const int*   __restrict__ s_node,
                 const int*   __restrict__ t_node,
                 const float* __restrict__ s_t_time,
                 const int*   __restrict__ mp_src,
                 const int*   __restrict__ mp_dst,
                 const float* __restrict__ mp_time,
                 const int*   __restrict__ mp_dist,
                 const int*   __restrict__ mp_type,
                 const int*   __restrict__ neg_node,
                 const int*   __restrict__ neg_mp_src,
                 const int*   __restrict__ neg_mp_dst,
                 const float* __restrict__ neg_mp_time,
                 const int*   __restrict__ neg_mp_dist,
                 const int*   __restrict__ neg_mp_type,
                 float* __restrict__ out)
{
    __shared__ float slots[1 + Q];
    __shared__ float s_dis[E];
    __shared__ float s_mp[MPT];

    const int b   = blockIdx.x;
    const int tid = threadIdx.x;

    if (tid < 1 + Q) slots[tid] = 0.f;
    block_softmaxes(distance_att, metapath_att, s_dis, s_mp, tid);
    __syncthreads();

    const int   s    = s_node[b];
    const int   t    = t_node[b];
    const float tt   = s_t_time[b];
    const float dss  = delta[s];
    const float dsdt = dss * delta[t];

    const int wave = tid >> 6;   // 0..7
    const int ln   = tid & 63;   // lane in wave

    for (int task = wave; task < TASKS; task += 8) {
        int srcn, dstn, slot;
        float wgt;
        decode_task(task, b, s, t, tt, dss, dsdt, delta, s_dis, s_mp,
                    mp_src, mp_dst, mp_time, mp_dist, mp_type,
                    neg_node, neg_mp_src, neg_mp_dst, neg_mp_time,
                    neg_mp_dist, neg_mp_type, srcn, dstn, slot, wgt);

        // v[j] = sum_i emb[src][i] * W[i][j]; lane ln owns cols ln and ln+64
        const float* erow = emb + (size_t)srcn * D;
        float v0 = 0.f, v1 = 0.f;
#pragma unroll 1
        for (int i = 0; i < D; ++i) {
            float a = erow[i];                    // broadcast across wave
            v0 = fmaf(a, W[i * D + ln], v0);      // coalesced 64-lane read
            v1 = fmaf(a, W[i * D + ln + 64], v1);
        }
        const float* drow = emb + (size_t)dstn * D;
        float d = v0 * drow[ln] + v1 * drow[ln + 64];
        // full 64-lane reduce
        d += __shfl_xor(d, 32);
        d += __shfl_xor(d, 16);
        d += __shfl_xor(d, 8);
        d += __shfl_xor(d, 4);
        d += __shfl_xor(d, 2);
        d += __shfl_xor(d, 1);
        if (ln == 0) atomicAdd(&slots[slot], d * wgt);
    }
    __syncthreads();

    if (tid == 0) epilogue(slots, out, b);
}

// ---------------------------------------------------------------------------
extern "C" void kernel_launch(void* const* d_in, const int* in_sizes, int n_in,
                              void* d_out, int out_size, void* d_ws, size_t ws_size,
                              hipStream_t stream)
{
    const float* emb          = (const float*)d_in[0];
    const float* delta        = (const float*)d_in[1];
    const float* W            = (const float*)d_in[2];
    const float* distance_att = (const float*)d_in[3];
    const float* metapath_att = (const float*)d_in[4];
    const int*   s_node       = (const int*)d_in[5];
    const int*   t_node       = (const int*)d_in[6];
    const float* s_t_time     = (const float*)d_in[7];
    const int*   mp_src       = (const int*)d_in[8];
    const int*   mp_dst       = (const int*)d_in[9];
    const float* mp_time      = (const float*)d_in[10];
    const int*   mp_dist      = (const int*)d_in[11];
    const int*   mp_type      = (const int*)d_in[12];
    const int*   neg_node     = (const int*)d_in[13];
    const int*   neg_mp_src   = (const int*)d_in[14];
    const int*   neg_mp_dst   = (const int*)d_in[15];
    const float* neg_mp_time  = (const float*)d_in[16];
    const int*   neg_mp_dist  = (const int*)d_in[17];
    const int*   neg_mp_type  = (const int*)d_in[18];

    const int N = in_sizes[1];       // delta has N elements
    const int B = in_sizes[5];       // s_node has B elements

    const size_t need = (size_t)N * D * sizeof(float);   // 51.2 MB

    if (ws_size >= need) {
        // Fast path: precompute embW = emb @ W, then gather-dots.
        float* embW = (float*)d_ws;
        int blocks1 = (N + 255) / 256;
        embw_gemm<<<blocks1, 512, 0, stream>>>(emb, W, embW, N);
        pair_kernel<<<B, 1024, 0, stream>>>(emb, embW, delta,
                                            distance_att, metapath_att,
                                            s_node, t_node, s_t_time,
                                            mp_src, mp_dst, mp_time, mp_dist, mp_type,
                                            neg_node, neg_mp_src, neg_mp_dst,
                                            neg_mp_time, neg_mp_dist, neg_mp_type,
                                            (float*)d_out);
    } else {
        // Fallback: direct evaluation, no workspace needed.
        pair_direct<<<B, 512, 0, stream>>>(emb, W, delta,
                                           distance_att, metapath_att,
                                           s_node, t_node, s_t_time,
                                           mp_src, mp_dst, mp_time, mp_dist, mp_type,
                                           neg_node, neg_mp_src, neg_mp_dst,
                                           neg_mp_time, neg_mp_dist, neg_mp_type,
                                           (float*)d_out);
    }
}